// Round 7
// baseline (253.481 us; speedup 1.0000x reference)
//
#include <hip/hip_runtime.h>

// Batched 16x16 Sinkhorn (VotingLayer) via scaling vectors, 4 lanes/matrix.
// S_t = diag(r)*S0*diag(c), S0 = v^T + 1e-6;  c = 1/(S0^T r), r = 1/(S0 c).
//
// Round-2 layout (best issue-efficiency: ~22.5 cyc/mat/iter vs 128 for the
// 16-lane layout) with its register disaster fixed:
//  - #pragma unroll 1 on the iteration loop (serial dep chain; full unroll
//    inflated live ranges to 208 VGPRs -> 2 waves/SIMD in round 2)
//  - __launch_bounds__(256, 4) caps allocation at 128 VGPRs
// Lane c (tid&3) owns global columns 4c..4c+3 of S0 = v rows 4c..4c+3
// (64 contiguous floats). Column phase: fully lane-local -> 4 distinct rcps,
// ZERO redundancy (the 16-lane layouts waste 4x on quad-redundant rcps, and
// rcp at quarter rate was half the issue budget). Row phase: per-lane v2f
// partials, quad_perm DPP allreduce, 16 rcps (4x redundant, unavoidable here).
// All FMAs packed (v_pk_fma_f32) via float2 ext-vectors.

#define NITER 10
typedef float v2f __attribute__((ext_vector_type(2)));

template <int CTRL>
__device__ __forceinline__ float dpp_add(float x) {
    int xi = __builtin_bit_cast(int, x);
    int yi = __builtin_amdgcn_update_dpp(xi, xi, CTRL, 0xF, 0xF, false);
    return x + __builtin_bit_cast(float, yi);
}

__device__ __forceinline__ float qsum(float x) {  // all-reduce over a quad
    x = dpp_add<0xB1>(x);   // quad_perm [1,0,3,2]  (xor 1)
    x = dpp_add<0x4E>(x);   // quad_perm [2,3,0,1]  (xor 2)
    return x;
}

__global__ __launch_bounds__(256, 4) void sinkhorn16_kernel(
        const float* __restrict__ v, float* __restrict__ out, int nmat) {
    const int tid = blockIdx.x * 256 + threadIdx.x;
    const int b   = tid >> 2;
    if (b >= nmat) return;
    const int c   = tid & 3;

    // Lane's 64 floats are contiguous: v[b][4c+0..4c+3][0..15].
    const float* base = v + (size_t)b * 256 + c * 64;
    // col[j][i2] = (S0[2*i2][4c+j], S0[2*i2+1][4c+j])
    v2f col[4][8];
#pragma unroll
    for (int j = 0; j < 4; ++j) {
#pragma unroll
        for (int g = 0; g < 4; ++g) {
            float4 f = *(const float4*)(base + j * 16 + g * 4);
            col[j][2 * g]     = (v2f){f.x + 1e-6f, f.y + 1e-6f};
            col[j][2 * g + 1] = (v2f){f.z + 1e-6f, f.w + 1e-6f};
        }
    }

    v2f rv[8];
#pragma unroll
    for (int i2 = 0; i2 < 8; ++i2) rv[i2] = (v2f){1.0f, 1.0f};
    float cj[4];

#pragma unroll 1
    for (int it = 0; it < NITER; ++it) {
        // ---- c = 1/(S0^T r): lane-local over its 4 columns ----
#pragma unroll
        for (int j = 0; j < 4; ++j) {
            v2f acc = col[j][0] * rv[0];
#pragma unroll
            for (int i2 = 1; i2 < 8; ++i2) acc += col[j][i2] * rv[i2];
            cj[j] = __builtin_amdgcn_rcpf(acc.x + acc.y);
        }
        // ---- r = 1/(S0 c): partial over own columns, quad all-reduce ----
        const v2f c0 = (v2f){cj[0], cj[0]};
        const v2f c1 = (v2f){cj[1], cj[1]};
        const v2f c2 = (v2f){cj[2], cj[2]};
        const v2f c3 = (v2f){cj[3], cj[3]};
#pragma unroll
        for (int i2 = 0; i2 < 8; ++i2) {
            v2f p =  col[0][i2] * c0;
            p     += col[1][i2] * c1;
            p     += col[2][i2] * c2;
            p     += col[3][i2] * c3;
            rv[i2].x = __builtin_amdgcn_rcpf(qsum(p.x));
            rv[i2].y = __builtin_amdgcn_rcpf(qsum(p.y));
        }
    }

    // ---- epilogue: out[i][4c+j] = r[i] * S0[i][4c+j] * c[4c+j] ----
    const v2f c0 = (v2f){cj[0], cj[0]};
    const v2f c1 = (v2f){cj[1], cj[1]};
    const v2f c2 = (v2f){cj[2], cj[2]};
    const v2f c3 = (v2f){cj[3], cj[3]};
    float* ob = out + (size_t)b * 256 + c * 4;
#pragma unroll
    for (int i2 = 0; i2 < 8; ++i2) {
        v2f s0 = col[0][i2] * rv[i2] * c0;
        v2f s1 = col[1][i2] * rv[i2] * c1;
        v2f s2 = col[2][i2] * rv[i2] * c2;
        v2f s3 = col[3][i2] * rv[i2] * c3;
        *(float4*)(ob + (2 * i2) * 16)     = make_float4(s0.x, s1.x, s2.x, s3.x);
        *(float4*)(ob + (2 * i2 + 1) * 16) = make_float4(s0.y, s1.y, s2.y, s3.y);
    }
}

extern "C" void kernel_launch(void* const* d_in, const int* in_sizes, int n_in,
                              void* d_out, int out_size, void* d_ws, size_t ws_size,
                              hipStream_t stream) {
    const float* v = (const float*)d_in[0];
    float* out = (float*)d_out;
    const int nmat = in_sizes[0] >> 8;           // 131072
    const int total_threads = nmat * 4;          // 4 lanes per matrix
    const int block = 256;
    const int grid = (total_threads + block - 1) / block;  // 2048
    sinkhorn16_kernel<<<grid, block, 0, stream>>>(v, out, nmat);
}

// Round 8
// 229.514 us; speedup vs baseline: 1.1044x; 1.1044x over previous
//
#include <hip/hip_runtime.h>

// Batched 16x16 Sinkhorn (VotingLayer), scaling-vector algorithm, with
// LDS-staged COALESCED global I/O.
//
// Round 1-7 finding: every register-direct variant pins at ~2.3 TB/s HBM
// (dur == bytes/2.3TB/s regardless of VALU work) because lanes access 16B
// chunks at 256B stride -> 64 partially-covered cache lines per wave-instr.
// Fix: block of 256 threads stages 16 matrices (16KB) through LDS; all
// global loads/stores are contiguous 1KB per wave instruction (the 6.3TB/s
// microbench pattern). Strided accesses hit LDS instead (2-way quad-group
// imbalance only ~= free).
//
// Compute core = round 3 (best measured): 16 lanes/matrix, lane idx: r=idx&3,
// c=idx>>2 owns 4x4 block bp[i][j]=S0[4r+i][4c+j]; S0 = v^T + 1e-6.
//   c = 1/(S0^T r): quad_perm DPP allreduce (lane bits 0-1)
//   r = 1/(S0 c):   row_ror:4/8 DPP allreduce (lane bits 2-3)
// Output: diag(r)*S0*diag(c).
// Barriers: stage-in->fj-read is cross-wave (sync 1); result-write->copy-out
// is cross-wave (sync 2); fj-read->result-write is same-wave only (no sync).

#define NITER 10
typedef float v2f __attribute__((ext_vector_type(2)));

template <int CTRL>
__device__ __forceinline__ float dpp_add(float x) {
    int xi = __builtin_bit_cast(int, x);
    int yi = __builtin_amdgcn_update_dpp(xi, xi, CTRL, 0xF, 0xF, false);
    return x + __builtin_bit_cast(float, yi);
}

__global__ __launch_bounds__(256) void sinkhorn16_kernel(
        const float* __restrict__ v, float* __restrict__ out, int nmat) {
    __shared__ float lds[4096];                       // 16 matrices = 16 KB
    float4* lds4 = (float4*)lds;

    const int t       = threadIdx.x;
    const int blk_mat = blockIdx.x * 16;
    const float4* g4  = (const float4*)(v + (size_t)blk_mat * 256);
    float4* o4        = (float4*)(out + (size_t)blk_mat * 256);

    // ---- stage in: contiguous 1KB per wave-instruction ----
#pragma unroll
    for (int k = 0; k < 4; ++k) {
        const int i4 = k * 256 + t;
        lds4[i4] = g4[i4];
    }
    __syncthreads();

    // ---- gather strided fragments from LDS ----
    const int m_blk = t >> 4;          // matrix 0..15 within block
    const int idx   = t & 15;
    const int r     = idx & 3;
    const int c     = idx >> 2;

    float4 fj[4];                      // fj[j] = S0 col-block: v[m][4c+j][4r..4r+3]
#pragma unroll
    for (int j = 0; j < 4; ++j)
        fj[j] = lds4[m_blk * 64 + (4 * c + j) * 4 + r];

    // bp[i][j2] = (blk[i][2*j2], blk[i][2*j2+1]) + 1e-6
    v2f bp[4][2];
#pragma unroll
    for (int j2 = 0; j2 < 2; ++j2) {
        const float4 fa = fj[2 * j2], fb = fj[2 * j2 + 1];
        bp[0][j2] = (v2f){fa.x + 1e-6f, fb.x + 1e-6f};
        bp[1][j2] = (v2f){fa.y + 1e-6f, fb.y + 1e-6f};
        bp[2][j2] = (v2f){fa.z + 1e-6f, fb.z + 1e-6f};
        bp[3][j2] = (v2f){fa.w + 1e-6f, fb.w + 1e-6f};
    }

    float rv[4] = {1.0f, 1.0f, 1.0f, 1.0f};
    v2f cjp[2];

#pragma unroll
    for (int it = 0; it < NITER; ++it) {
        // ---- column phase: c_j = 1/sum_i S0[i][j]*r_i ----
#pragma unroll
        for (int j2 = 0; j2 < 2; ++j2) {
            v2f acc = bp[0][j2] * (v2f){rv[0], rv[0]};
            acc += bp[1][j2] * (v2f){rv[1], rv[1]};
            acc += bp[2][j2] * (v2f){rv[2], rv[2]};
            acc += bp[3][j2] * (v2f){rv[3], rv[3]};
            float s0 = dpp_add<0x4E>(dpp_add<0xB1>(acc.x));   // xor 1, xor 2
            float s1 = dpp_add<0x4E>(dpp_add<0xB1>(acc.y));
            cjp[j2] = (v2f){__builtin_amdgcn_rcpf(s0), __builtin_amdgcn_rcpf(s1)};
        }
        // ---- row phase: r_i = 1/sum_j S0[i][j]*c_j ----
#pragma unroll
        for (int i = 0; i < 4; ++i) {
            v2f tacc = bp[i][0] * cjp[0] + bp[i][1] * cjp[1];
            float s = dpp_add<0x128>(dpp_add<0x124>(tacc.x + tacc.y)); // ror 4, 8
            rv[i] = __builtin_amdgcn_rcpf(s);
        }
    }

    // ---- results back to LDS (same-wave region: no barrier needed before) ----
#pragma unroll
    for (int i = 0; i < 4; ++i) {
        const v2f rvp = (v2f){rv[i], rv[i]};
        const v2f s0 = bp[i][0] * cjp[0] * rvp;
        const v2f s1 = bp[i][1] * cjp[1] * rvp;
        lds4[m_blk * 64 + (4 * r + i) * 4 + c] = make_float4(s0.x, s0.y, s1.x, s1.y);
    }
    __syncthreads();

    // ---- stage out: contiguous 1KB per wave-instruction ----
#pragma unroll
    for (int k = 0; k < 4; ++k) {
        const int i4 = k * 256 + t;
        o4[i4] = lds4[i4];
    }
}

extern "C" void kernel_launch(void* const* d_in, const int* in_sizes, int n_in,
                              void* d_out, int out_size, void* d_ws, size_t ws_size,
                              hipStream_t stream) {
    const float* v = (const float*)d_in[0];
    float* out = (float*)d_out;
    const int nmat = in_sizes[0] >> 8;            // 131072
    const int grid = nmat / 16;                   // 16 matrices per block -> 8192
    sinkhorn16_kernel<<<grid, 256, 0, stream>>>(v, out, nmat);
}